// Round 1
// baseline (2768.142 us; speedup 1.0000x reference)
//
#include <hip/hip_runtime.h>
#include <hip/hip_bf16.h>
#include <stdint.h>

#define NN 50000
#define NE 1600000
#define NG 64
#define FIN 256
#define HD 1024
#define EPSV 1e-5f

typedef __bf16 bf16;
typedef __bf16 bf16x4 __attribute__((ext_vector_type(4)));
typedef __bf16 bf16x8 __attribute__((ext_vector_type(8)));
typedef float f32x4 __attribute__((ext_vector_type(4)));

typedef const __attribute__((address_space(1))) void* gptr_as1;
typedef __attribute__((address_space(3))) void* lptr_as3;

__device__ __forceinline__ void load_g2l_16(const void* g, const void* l) {
  __builtin_amdgcn_global_load_lds((gptr_as1)(uintptr_t)g,
                                   (lptr_as3)(uint32_t)(uintptr_t)l, 16, 0, 0);
}

// ---------------- degree histogram / dinv ----------------
__global__ void hist_kernel(const int* __restrict__ col, int* __restrict__ cnt, int E) {
  int e = blockIdx.x * 256 + threadIdx.x;
  if (e < E) atomicAdd(&cnt[col[e]], 1);
}

__global__ void dinv_kernel(const int* __restrict__ cnt, float* __restrict__ dinv, int n) {
  int i = blockIdx.x * 256 + threadIdx.x;
  if (i < n) dinv[i] = rsqrtf((float)(cnt[i] + 1));  // +1 self-loop
}

// ---------------- exclusive scan (3-phase) ----------------
__global__ void scan_partial_kernel(const int* __restrict__ cnt, int* __restrict__ partial, int n) {
  __shared__ int red[4];
  int i = blockIdx.x * 256 + threadIdx.x;
  int v = (i < n) ? cnt[i] : 0;
  #pragma unroll
  for (int off = 32; off; off >>= 1) v += __shfl_down(v, off, 64);
  if ((threadIdx.x & 63) == 0) red[threadIdx.x >> 6] = v;
  __syncthreads();
  if (threadIdx.x == 0) partial[blockIdx.x] = red[0] + red[1] + red[2] + red[3];
}

__global__ void scan_scan_kernel(int* __restrict__ partial, int nb) {
  __shared__ int s[256];
  int t = threadIdx.x;
  int v = (t < nb) ? partial[t] : 0;
  s[t] = v;
  __syncthreads();
  for (int off = 1; off < 256; off <<= 1) {
    int x = (t >= off) ? s[t - off] : 0;
    __syncthreads();
    s[t] += x;
    __syncthreads();
  }
  if (t < nb) partial[t] = s[t] - v;  // exclusive
}

__global__ void scan_final_kernel(const int* __restrict__ cnt, const int* __restrict__ partial,
                                  int* __restrict__ row_ptr, int n, int E) {
  __shared__ int s[256];
  int t = threadIdx.x;
  int i = blockIdx.x * 256 + t;
  int v = (i < n) ? cnt[i] : 0;
  s[t] = v;
  __syncthreads();
  for (int off = 1; off < 256; off <<= 1) {
    int x = (t >= off) ? s[t - off] : 0;
    __syncthreads();
    s[t] += x;
    __syncthreads();
  }
  if (i < n) row_ptr[i] = partial[blockIdx.x] + s[t] - v;
  if (i == 0) row_ptr[n] = E;
}

// ---------------- CSR scatter ----------------
__global__ void scatter_kernel(const int* __restrict__ rowi, const int* __restrict__ coli,
                               const int* __restrict__ row_ptr, int* __restrict__ fill,
                               const float* __restrict__ dinv,
                               int* __restrict__ csr_src, float* __restrict__ csr_w, int E) {
  int e = blockIdx.x * 256 + threadIdx.x;
  if (e >= E) return;
  int s = rowi[e], d = coli[e];
  int pos = row_ptr[d] + atomicAdd(&fill[d], 1);
  csr_src[pos] = s;
  csr_w[pos] = dinv[s] * dinv[d];
}

// ---------------- f32 -> bf16 convert ----------------
__global__ void cvt_kernel(const float* __restrict__ in, bf16* __restrict__ out, int n4) {
  int i = blockIdx.x * 256 + threadIdx.x;
  if (i >= n4) return;
  float4 v = ((const float4*)in)[i];
  bf16x4 o = { (bf16)v.x, (bf16)v.y, (bf16)v.z, (bf16)v.w };
  ((bf16x4*)out)[i] = o;
}

// ---------------- W [K][N] f32 -> Wt [N][K] bf16 ----------------
__global__ void transpose_w_kernel(const float* __restrict__ W, bf16* __restrict__ Wt,
                                   int K, int N) {
  __shared__ float tile[32][33];
  int n0 = blockIdx.x * 32, k0 = blockIdx.y * 32;
  int tx = threadIdx.x, ty = threadIdx.y;  // 32 x 8
  #pragma unroll
  for (int i = ty; i < 32; i += 8) tile[i][tx] = W[(size_t)(k0 + i) * N + n0 + tx];
  __syncthreads();
  #pragma unroll
  for (int i = ty; i < 32; i += 8) Wt[(size_t)(n0 + i) * K + k0 + tx] = (bf16)tile[tx][i];
}

// ---------------- bf16 MFMA GEMM: C[M][1024] = A[M][K] * Wt[1024][K]^T ----------------
__global__ __launch_bounds__(256, 2) void gemm_bt_kernel(
    const bf16* __restrict__ A, const bf16* __restrict__ Bt,
    bf16* __restrict__ C, int M, int K) {
  __shared__ __align__(16) bf16 As[128 * 32];
  __shared__ __align__(16) bf16 Bs[128 * 32];
  const int tid = threadIdx.x;
  const int w = tid >> 6, l = tid & 63;
  const int m0 = blockIdx.y * 128, n0 = blockIdx.x * 128;
  const int wr = w >> 1, wc = w & 1;  // 2x2 wave grid, each wave 64x64

  f32x4 acc[4][4] = {};

  const int r0 = tid >> 2;            // 0..63
  const int c8 = (tid & 3) * 8;       // k offset within BK=32
  int ar0 = m0 + r0;       if (ar0 >= M) ar0 = M - 1;
  int ar1 = m0 + r0 + 64;  if (ar1 >= M) ar1 = M - 1;
  const bf16* a0 = A + (size_t)ar0 * K + c8;
  const bf16* a1 = A + (size_t)ar1 * K + c8;
  const bf16* b0 = Bt + (size_t)(n0 + r0) * K + c8;
  const bf16* b1 = Bt + (size_t)(n0 + r0 + 64) * K + c8;
  bf16* asw = As + w * 512;   // wave-uniform LDS dest (bytes: w*1024)
  bf16* bsw = Bs + w * 512;

  const int mrow = l & 15;
  const int kch = (l >> 4) * 8;

  for (int k = 0; k < K; k += 32) {
    load_g2l_16(a0 + k, asw);
    load_g2l_16(a1 + k, asw + 2048);
    load_g2l_16(b0 + k, bsw);
    load_g2l_16(b1 + k, bsw + 2048);
    __syncthreads();   // drains vmcnt before barrier (compiler-inserted)
    bf16x8 af[4], bf_[4];
    #pragma unroll
    for (int m = 0; m < 4; m++)
      af[m] = *(const bf16x8*)&As[(wr * 64 + m * 16 + mrow) * 32 + kch];
    #pragma unroll
    for (int n = 0; n < 4; n++)
      bf_[n] = *(const bf16x8*)&Bs[(wc * 64 + n * 16 + mrow) * 32 + kch];
    #pragma unroll
    for (int m = 0; m < 4; m++)
      #pragma unroll
      for (int n = 0; n < 4; n++)
        acc[m][n] = __builtin_amdgcn_mfma_f32_16x16x32_bf16(af[m], bf_[n], acc[m][n], 0, 0, 0);
    __syncthreads();
  }

  #pragma unroll
  for (int m = 0; m < 4; m++) {
    int grow = m0 + wr * 64 + m * 16 + (l >> 4) * 4;
    #pragma unroll
    for (int n = 0; n < 4; n++) {
      int gcol = n0 + wc * 64 + n * 16 + (l & 15);
      #pragma unroll
      for (int r = 0; r < 4; r++) {
        if (grow + r < M) C[(size_t)(grow + r) * HD + gcol] = (bf16)acc[m][n][r];
      }
    }
  }
}

// ---------------- fused aggregate + bias + LayerNorm + ReLU ----------------
__global__ __launch_bounds__(256) void agg_ln_kernel(
    const bf16* __restrict__ ht, const int* __restrict__ row_ptr,
    const int* __restrict__ csr_src, const float* __restrict__ csr_w,
    const float* __restrict__ dinv, const float* __restrict__ bias,
    const float* __restrict__ gamma, const float* __restrict__ beta,
    bf16* __restrict__ hout) {
  const int node = blockIdx.x;
  const int t = threadIdx.x;
  __shared__ float red[4];

  // self-loop
  float dn = dinv[node];
  float wself = dn * dn;
  bf16x4 v = ((const bf16x4*)(ht + (size_t)node * HD))[t];
  f32x4 acc;
  acc[0] = wself * (float)v[0];
  acc[1] = wself * (float)v[1];
  acc[2] = wself * (float)v[2];
  acc[3] = wself * (float)v[3];

  const int e1 = row_ptr[node + 1];
  for (int e = row_ptr[node]; e < e1; e++) {
    int src = csr_src[e];
    float wgt = csr_w[e];
    bf16x4 u = ((const bf16x4*)(ht + (size_t)src * HD))[t];
    acc[0] += wgt * (float)u[0];
    acc[1] += wgt * (float)u[1];
    acc[2] += wgt * (float)u[2];
    acc[3] += wgt * (float)u[3];
  }
  float4 b4 = ((const float4*)bias)[t];
  acc[0] += b4.x; acc[1] += b4.y; acc[2] += b4.z; acc[3] += b4.w;

  // mean
  float s = acc[0] + acc[1] + acc[2] + acc[3];
  #pragma unroll
  for (int off = 32; off; off >>= 1) s += __shfl_down(s, off, 64);
  if ((t & 63) == 0) red[t >> 6] = s;
  __syncthreads();
  float mean = (red[0] + red[1] + red[2] + red[3]) * (1.0f / HD);
  __syncthreads();

  float d0 = acc[0] - mean, d1 = acc[1] - mean, d2 = acc[2] - mean, d3 = acc[3] - mean;
  float s2 = d0 * d0 + d1 * d1 + d2 * d2 + d3 * d3;
  #pragma unroll
  for (int off = 32; off; off >>= 1) s2 += __shfl_down(s2, off, 64);
  if ((t & 63) == 0) red[t >> 6] = s2;
  __syncthreads();
  float var = (red[0] + red[1] + red[2] + red[3]) * (1.0f / HD);
  float rstd = rsqrtf(var + EPSV);

  float4 g4 = ((const float4*)gamma)[t];
  float4 be4 = ((const float4*)beta)[t];
  float o0 = fmaxf(d0 * rstd * g4.x + be4.x, 0.0f);
  float o1 = fmaxf(d1 * rstd * g4.y + be4.y, 0.0f);
  float o2 = fmaxf(d2 * rstd * g4.z + be4.z, 0.0f);
  float o3 = fmaxf(d3 * rstd * g4.w + be4.w, 0.0f);
  bf16x4 o = { (bf16)o0, (bf16)o1, (bf16)o2, (bf16)o3 };
  ((bf16x4*)(hout + (size_t)node * HD))[t] = o;
}

// ---------------- graph boundaries (batch is sorted) ----------------
__global__ void starts_kernel(const int* __restrict__ batch, int* __restrict__ start,
                              int n, int ngraph) {
  int g = blockIdx.x * blockDim.x + threadIdx.x;
  if (g > ngraph) return;
  int lo = 0, hi = n;
  while (lo < hi) {
    int mid = (lo + hi) >> 1;
    if (batch[mid] < g) lo = mid + 1; else hi = mid;
  }
  start[g] = lo;
}

// ---------------- mean-pool per graph ----------------
__global__ void pool_kernel(const bf16* __restrict__ h, const int* __restrict__ start,
                            float* __restrict__ out) {
  int g = blockIdx.y;
  int t = threadIdx.x;
  int s0 = start[g], s1 = start[g + 1];
  f32x4 acc = {0.f, 0.f, 0.f, 0.f};
  for (int n = s0; n < s1; n++) {
    bf16x4 v = ((const bf16x4*)(h + (size_t)n * HD))[t];
    acc[0] += (float)v[0]; acc[1] += (float)v[1];
    acc[2] += (float)v[2]; acc[3] += (float)v[3];
  }
  float inv = 1.0f / (float)max(s1 - s0, 1);
  float4 o = { acc[0] * inv, acc[1] * inv, acc[2] * inv, acc[3] * inv };
  ((float4*)(out + (size_t)g * HD))[t] = o;
}

extern "C" void kernel_launch(void* const* d_in, const int* in_sizes, int n_in,
                              void* d_out, int out_size, void* d_ws, size_t ws_size,
                              hipStream_t stream) {
  const float* x      = (const float*)d_in[0];
  const int*   eidx   = (const int*)d_in[1];
  const int*   batch  = (const int*)d_in[2];
  const float* W0     = (const float*)d_in[3];
  const float* b0     = (const float*)d_in[4];
  const float* Ws     = (const float*)d_in[5];
  const float* bs     = (const float*)d_in[6];
  const float* gammas = (const float*)d_in[7];
  const float* betas  = (const float*)d_in[8];
  float* out = (float*)d_out;

  const int* erow = eidx;        // sources
  const int* ecol = eidx + NE;   // targets

  char* ws = (char*)d_ws;
  size_t off = 0;
  auto alloc = [&](size_t bytes) {
    void* p = ws + off;
    off = (off + bytes + 255) & ~(size_t)255;
    return p;
  };
  int*   cnt     = (int*)alloc((size_t)NN * 4);
  int*   row_ptr = (int*)alloc((size_t)(NN + 1) * 4);
  int*   fill    = (int*)alloc((size_t)NN * 4);
  int*   partial = (int*)alloc(256 * 4);
  float* dinv    = (float*)alloc((size_t)NN * 4);
  int*   csr_src = (int*)alloc((size_t)NE * 4);
  float* csr_w   = (float*)alloc((size_t)NE * 4);
  bf16*  Wt      = (bf16*)alloc((size_t)HD * HD * 2);
  bf16*  hbuf    = (bf16*)alloc((size_t)NN * HD * 2);
  bf16*  htbuf   = (bf16*)alloc((size_t)NN * HD * 2);
  int*   gstart  = (int*)alloc(65 * 4);

  hipMemsetAsync(cnt, 0, (size_t)NN * 4, stream);
  hipMemsetAsync(fill, 0, (size_t)NN * 4, stream);

  hist_kernel<<<(NE + 255) / 256, 256, 0, stream>>>(ecol, cnt, NE);
  dinv_kernel<<<(NN + 255) / 256, 256, 0, stream>>>(cnt, dinv, NN);
  int nb = (NN + 255) / 256;  // 196
  scan_partial_kernel<<<nb, 256, 0, stream>>>(cnt, partial, NN);
  scan_scan_kernel<<<1, 256, 0, stream>>>(partial, nb);
  scan_final_kernel<<<nb, 256, 0, stream>>>(cnt, partial, row_ptr, NN, NE);
  scatter_kernel<<<(NE + 255) / 256, 256, 0, stream>>>(erow, ecol, row_ptr, fill, dinv,
                                                       csr_src, csr_w, NE);

  cvt_kernel<<<(NN * FIN / 4 + 255) / 256, 256, 0, stream>>>(x, hbuf, NN * FIN / 4);

  for (int L = 0; L < 4; L++) {
    int K = (L == 0) ? FIN : HD;
    const float* W    = (L == 0) ? W0 : Ws + (size_t)(L - 1) * HD * HD;
    const float* bias = (L == 0) ? b0 : bs + (size_t)(L - 1) * HD;
    transpose_w_kernel<<<dim3(HD / 32, K / 32), dim3(32, 8), 0, stream>>>(W, Wt, K, HD);
    gemm_bt_kernel<<<dim3(HD / 128, (NN + 127) / 128), 256, 0, stream>>>(hbuf, Wt, htbuf, NN, K);
    agg_ln_kernel<<<NN, 256, 0, stream>>>(htbuf, row_ptr, csr_src, csr_w, dinv, bias,
                                          gammas + (size_t)L * HD, betas + (size_t)L * HD, hbuf);
  }

  starts_kernel<<<1, 128, 0, stream>>>(batch, gstart, NN, NG);
  pool_kernel<<<dim3(1, NG), 256, 0, stream>>>(hbuf, gstart, out);
}

// Round 2
// 2577.076 us; speedup vs baseline: 1.0741x; 1.0741x over previous
//
#include <hip/hip_runtime.h>
#include <hip/hip_bf16.h>
#include <stdint.h>

#define NN 50000
#define NE 1600000
#define NG 64
#define FIN 256
#define HD 1024
#define EPSV 1e-5f

typedef __bf16 bf16;
typedef __bf16 bf16x4 __attribute__((ext_vector_type(4)));
typedef __bf16 bf16x8 __attribute__((ext_vector_type(8)));
typedef float f32x4 __attribute__((ext_vector_type(4)));

typedef const __attribute__((address_space(1))) void* gptr_as1;
typedef __attribute__((address_space(3))) void* lptr_as3;

__device__ __forceinline__ void load_g2l_16(const void* g, const void* l) {
  __builtin_amdgcn_global_load_lds((gptr_as1)(uintptr_t)g,
                                   (lptr_as3)(uint32_t)(uintptr_t)l, 16, 0, 0);
}

// ---------------- degree histogram / dinv ----------------
__global__ void hist_kernel(const int* __restrict__ col, int* __restrict__ cnt, int E) {
  int e = blockIdx.x * 256 + threadIdx.x;
  if (e < E) atomicAdd(&cnt[col[e]], 1);
}

__global__ void dinv_kernel(const int* __restrict__ cnt, float* __restrict__ dinv, int n) {
  int i = blockIdx.x * 256 + threadIdx.x;
  if (i < n) dinv[i] = rsqrtf((float)(cnt[i] + 1));  // +1 self-loop
}

// ---------------- exclusive scan (3-phase) ----------------
__global__ void scan_partial_kernel(const int* __restrict__ cnt, int* __restrict__ partial, int n) {
  __shared__ int red[4];
  int i = blockIdx.x * 256 + threadIdx.x;
  int v = (i < n) ? cnt[i] : 0;
  #pragma unroll
  for (int off = 32; off; off >>= 1) v += __shfl_down(v, off, 64);
  if ((threadIdx.x & 63) == 0) red[threadIdx.x >> 6] = v;
  __syncthreads();
  if (threadIdx.x == 0) partial[blockIdx.x] = red[0] + red[1] + red[2] + red[3];
}

__global__ void scan_scan_kernel(int* __restrict__ partial, int nb) {
  __shared__ int s[256];
  int t = threadIdx.x;
  int v = (t < nb) ? partial[t] : 0;
  s[t] = v;
  __syncthreads();
  for (int off = 1; off < 256; off <<= 1) {
    int x = (t >= off) ? s[t - off] : 0;
    __syncthreads();
    s[t] += x;
    __syncthreads();
  }
  if (t < nb) partial[t] = s[t] - v;  // exclusive
}

__global__ void scan_final_kernel(const int* __restrict__ cnt, const int* __restrict__ partial,
                                  int* __restrict__ row_ptr, int n, int E) {
  __shared__ int s[256];
  int t = threadIdx.x;
  int i = blockIdx.x * 256 + t;
  int v = (i < n) ? cnt[i] : 0;
  s[t] = v;
  __syncthreads();
  for (int off = 1; off < 256; off <<= 1) {
    int x = (t >= off) ? s[t - off] : 0;
    __syncthreads();
    s[t] += x;
    __syncthreads();
  }
  if (i < n) row_ptr[i] = partial[blockIdx.x] + s[t] - v;
  if (i == 0) row_ptr[n] = E;
}

// ---------------- CSR scatter ----------------
__global__ void scatter_kernel(const int* __restrict__ rowi, const int* __restrict__ coli,
                               const int* __restrict__ row_ptr, int* __restrict__ fill,
                               const float* __restrict__ dinv,
                               int* __restrict__ csr_src, float* __restrict__ csr_w, int E) {
  int e = blockIdx.x * 256 + threadIdx.x;
  if (e >= E) return;
  int s = rowi[e], d = coli[e];
  int pos = row_ptr[d] + atomicAdd(&fill[d], 1);
  csr_src[pos] = s;
  csr_w[pos] = dinv[s] * dinv[d];
}

// ---------------- f32 -> bf16 convert ----------------
__global__ void cvt_kernel(const float* __restrict__ in, bf16* __restrict__ out, int n4) {
  int i = blockIdx.x * 256 + threadIdx.x;
  if (i >= n4) return;
  float4 v = ((const float4*)in)[i];
  bf16x4 o = { (bf16)v.x, (bf16)v.y, (bf16)v.z, (bf16)v.w };
  ((bf16x4*)out)[i] = o;
}

// ---------------- W [K][N] f32 -> Wt [N][K] bf16 ----------------
__global__ void transpose_w_kernel(const float* __restrict__ W, bf16* __restrict__ Wt,
                                   int K, int N) {
  __shared__ float tile[32][33];
  int n0 = blockIdx.x * 32, k0 = blockIdx.y * 32;
  int tx = threadIdx.x, ty = threadIdx.y;  // 32 x 8
  #pragma unroll
  for (int i = ty; i < 32; i += 8) tile[i][tx] = W[(size_t)(k0 + i) * N + n0 + tx];
  __syncthreads();
  #pragma unroll
  for (int i = ty; i < 32; i += 8) Wt[(size_t)(n0 + i) * K + k0 + tx] = (bf16)tile[tx][i];
}

// ---------------- bf16 MFMA GEMM: C[M][1024] = A[M][K] * Wt[1024][K]^T ----------------
__global__ __launch_bounds__(256, 2) void gemm_bt_kernel(
    const bf16* __restrict__ A, const bf16* __restrict__ Bt,
    bf16* __restrict__ C, int M, int K) {
  __shared__ __align__(16) bf16 As[128 * 32];
  __shared__ __align__(16) bf16 Bs[128 * 32];
  const int tid = threadIdx.x;
  const int w = tid >> 6, l = tid & 63;
  const int m0 = blockIdx.y * 128, n0 = blockIdx.x * 128;
  const int wr = w >> 1, wc = w & 1;  // 2x2 wave grid, each wave 64x64

  f32x4 acc[4][4] = {};

  const int r0 = tid >> 2;            // 0..63
  const int c8 = (tid & 3) * 8;       // k offset within BK=32
  int ar0 = m0 + r0;       if (ar0 >= M) ar0 = M - 1;
  int ar1 = m0 + r0 + 64;  if (ar1 >= M) ar1 = M - 1;
  const bf16* a0 = A + (size_t)ar0 * K + c8;
  const bf16* a1 = A + (size_t)ar1 * K + c8;
  const bf16* b0 = Bt + (size_t)(n0 + r0) * K + c8;
  const bf16* b1 = Bt + (size_t)(n0 + r0 + 64) * K + c8;
  bf16* asw = As + w * 512;   // wave-uniform LDS dest (bytes: w*1024)
  bf16* bsw = Bs + w * 512;

  const int mrow = l & 15;
  const int kch = (l >> 4) * 8;

  for (int k = 0; k < K; k += 32) {
    load_g2l_16(a0 + k, asw);
    load_g2l_16(a1 + k, asw + 2048);
    load_g2l_16(b0 + k, bsw);
    load_g2l_16(b1 + k, bsw + 2048);
    __syncthreads();   // drains vmcnt before barrier (compiler-inserted)
    bf16x8 af[4], bf_[4];
    #pragma unroll
    for (int m = 0; m < 4; m++)
      af[m] = *(const bf16x8*)&As[(wr * 64 + m * 16 + mrow) * 32 + kch];
    #pragma unroll
    for (int n = 0; n < 4; n++)
      bf_[n] = *(const bf16x8*)&Bs[(wc * 64 + n * 16 + mrow) * 32 + kch];
    #pragma unroll
    for (int m = 0; m < 4; m++)
      #pragma unroll
      for (int n = 0; n < 4; n++)
        acc[m][n] = __builtin_amdgcn_mfma_f32_16x16x32_bf16(af[m], bf_[n], acc[m][n], 0, 0, 0);
    __syncthreads();
  }

  #pragma unroll
  for (int m = 0; m < 4; m++) {
    int grow = m0 + wr * 64 + m * 16 + (l >> 4) * 4;
    #pragma unroll
    for (int n = 0; n < 4; n++) {
      int gcol = n0 + wc * 64 + n * 16 + (l & 15);
      #pragma unroll
      for (int r = 0; r < 4; r++) {
        if (grow + r < M) C[(size_t)(grow + r) * HD + gcol] = (bf16)acc[m][n][r];
      }
    }
  }
}

// ---------------- fused aggregate + bias + LayerNorm + ReLU ----------------
// 2 nodes per 256-thread block: threads [0,128) -> node 2*b, [128,256) -> node 2*b+1.
// Each thread covers 8 columns (bf16x8 = 16B loads). Edge loop unrolled x4 for MLP.
__global__ __launch_bounds__(256) void agg_ln_kernel(
    const bf16* __restrict__ ht, const int* __restrict__ row_ptr,
    const int* __restrict__ csr_src, const float* __restrict__ csr_w,
    const float* __restrict__ dinv, const float* __restrict__ bias,
    const float* __restrict__ gamma, const float* __restrict__ beta,
    bf16* __restrict__ hout) {
  const int g = threadIdx.x >> 7;           // node-group within block (0/1)
  const int node = blockIdx.x * 2 + g;
  const int tt = threadIdx.x & 127;         // lane within group; cols [tt*8, tt*8+8)
  const int wid = threadIdx.x >> 6;         // wave id 0..3
  __shared__ float red[4];

  // self-loop
  float dn = dinv[node];
  float wself = dn * dn;
  bf16x8 v = ((const bf16x8*)(ht + (size_t)node * HD))[tt];
  float acc[8];
  #pragma unroll
  for (int j = 0; j < 8; j++) acc[j] = wself * (float)v[j];

  int e = row_ptr[node];
  const int e1 = row_ptr[node + 1];
  for (; e + 4 <= e1; e += 4) {
    int s0 = csr_src[e], s1 = csr_src[e + 1], s2 = csr_src[e + 2], s3 = csr_src[e + 3];
    float w0 = csr_w[e], w1 = csr_w[e + 1], w2 = csr_w[e + 2], w3 = csr_w[e + 3];
    bf16x8 u0 = ((const bf16x8*)(ht + (size_t)s0 * HD))[tt];
    bf16x8 u1 = ((const bf16x8*)(ht + (size_t)s1 * HD))[tt];
    bf16x8 u2 = ((const bf16x8*)(ht + (size_t)s2 * HD))[tt];
    bf16x8 u3 = ((const bf16x8*)(ht + (size_t)s3 * HD))[tt];
    #pragma unroll
    for (int j = 0; j < 8; j++)
      acc[j] += w0 * (float)u0[j] + w1 * (float)u1[j] + w2 * (float)u2[j] + w3 * (float)u3[j];
  }
  for (; e < e1; e++) {
    int src = csr_src[e];
    float wgt = csr_w[e];
    bf16x8 u = ((const bf16x8*)(ht + (size_t)src * HD))[tt];
    #pragma unroll
    for (int j = 0; j < 8; j++) acc[j] += wgt * (float)u[j];
  }

  const float4* bias2 = (const float4*)bias;
  float4 ba = bias2[tt * 2], bb = bias2[tt * 2 + 1];
  acc[0] += ba.x; acc[1] += ba.y; acc[2] += ba.z; acc[3] += ba.w;
  acc[4] += bb.x; acc[5] += bb.y; acc[6] += bb.z; acc[7] += bb.w;

  // mean (reduce over the 128 threads of this node-group: 2 waves)
  float s = 0.f;
  #pragma unroll
  for (int j = 0; j < 8; j++) s += acc[j];
  #pragma unroll
  for (int off = 32; off; off >>= 1) s += __shfl_down(s, off, 64);
  if ((threadIdx.x & 63) == 0) red[wid] = s;
  __syncthreads();
  float mean = (red[g * 2] + red[g * 2 + 1]) * (1.0f / HD);
  __syncthreads();

  float d[8], s2 = 0.f;
  #pragma unroll
  for (int j = 0; j < 8; j++) { d[j] = acc[j] - mean; s2 += d[j] * d[j]; }
  #pragma unroll
  for (int off = 32; off; off >>= 1) s2 += __shfl_down(s2, off, 64);
  if ((threadIdx.x & 63) == 0) red[wid] = s2;
  __syncthreads();
  float var = (red[g * 2] + red[g * 2 + 1]) * (1.0f / HD);
  float rstd = rsqrtf(var + EPSV);

  const float4* gam2 = (const float4*)gamma;
  const float4* bet2 = (const float4*)beta;
  float4 g0 = gam2[tt * 2], g1 = gam2[tt * 2 + 1];
  float4 be0 = bet2[tt * 2], be1 = bet2[tt * 2 + 1];
  float gv[8] = {g0.x, g0.y, g0.z, g0.w, g1.x, g1.y, g1.z, g1.w};
  float bv[8] = {be0.x, be0.y, be0.z, be0.w, be1.x, be1.y, be1.z, be1.w};
  bf16x8 o;
  #pragma unroll
  for (int j = 0; j < 8; j++) o[j] = (bf16)fmaxf(d[j] * rstd * gv[j] + bv[j], 0.0f);
  ((bf16x8*)(hout + (size_t)node * HD))[tt] = o;
}

// ---------------- graph boundaries (batch is sorted) ----------------
__global__ void starts_kernel(const int* __restrict__ batch, int* __restrict__ start,
                              int n, int ngraph) {
  int g = blockIdx.x * blockDim.x + threadIdx.x;
  if (g > ngraph) return;
  int lo = 0, hi = n;
  while (lo < hi) {
    int mid = (lo + hi) >> 1;
    if (batch[mid] < g) lo = mid + 1; else hi = mid;
  }
  start[g] = lo;
}

// ---------------- mean-pool per graph: partial sums + atomics ----------------
#define POOL_CHUNKS 8
__global__ void pool_partial_kernel(const bf16* __restrict__ h, const int* __restrict__ start,
                                    float* __restrict__ out) {
  int g = blockIdx.y, c = blockIdx.x;
  int t = threadIdx.x;
  int s0 = start[g], s1 = start[g + 1];
  int len = s1 - s0;
  int per = (len + POOL_CHUNKS - 1) / POOL_CHUNKS;
  int a = s0 + c * per;
  int b = min(a + per, s1);
  if (a >= b) return;
  f32x4 acc = {0.f, 0.f, 0.f, 0.f};
  for (int n = a; n < b; n++) {
    bf16x4 v = ((const bf16x4*)(h + (size_t)n * HD))[t];
    acc[0] += (float)v[0]; acc[1] += (float)v[1];
    acc[2] += (float)v[2]; acc[3] += (float)v[3];
  }
  float* o = out + (size_t)g * HD + t * 4;
  atomicAdd(o + 0, acc[0]);
  atomicAdd(o + 1, acc[1]);
  atomicAdd(o + 2, acc[2]);
  atomicAdd(o + 3, acc[3]);
}

__global__ void pool_div_kernel(float* __restrict__ out, const int* __restrict__ start) {
  int i = blockIdx.x * 256 + threadIdx.x;
  if (i >= NG * HD) return;
  int g = i >> 10;
  float c = (float)max(start[g + 1] - start[g], 1);
  out[i] = out[i] / c;
}

extern "C" void kernel_launch(void* const* d_in, const int* in_sizes, int n_in,
                              void* d_out, int out_size, void* d_ws, size_t ws_size,
                              hipStream_t stream) {
  const float* x      = (const float*)d_in[0];
  const int*   eidx   = (const int*)d_in[1];
  const int*   batch  = (const int*)d_in[2];
  const float* W0     = (const float*)d_in[3];
  const float* b0     = (const float*)d_in[4];
  const float* Ws     = (const float*)d_in[5];
  const float* bs     = (const float*)d_in[6];
  const float* gammas = (const float*)d_in[7];
  const float* betas  = (const float*)d_in[8];
  float* out = (float*)d_out;

  const int* erow = eidx;        // sources
  const int* ecol = eidx + NE;   // targets (aggregation index)

  char* ws = (char*)d_ws;
  size_t off = 0;
  auto alloc = [&](size_t bytes) {
    void* p = ws + off;
    off = (off + bytes + 255) & ~(size_t)255;
    return p;
  };
  int*   cnt     = (int*)alloc((size_t)NN * 4);
  int*   row_ptr = (int*)alloc((size_t)(NN + 1) * 4);
  int*   fill    = (int*)alloc((size_t)NN * 4);
  int*   partial = (int*)alloc(256 * 4);
  float* dinv    = (float*)alloc((size_t)NN * 4);
  int*   csr_src = (int*)alloc((size_t)NE * 4);
  float* csr_w   = (float*)alloc((size_t)NE * 4);
  bf16*  Wt      = (bf16*)alloc((size_t)HD * HD * 2);
  bf16*  hbuf    = (bf16*)alloc((size_t)NN * HD * 2);
  bf16*  htbuf   = (bf16*)alloc((size_t)NN * HD * 2);
  int*   gstart  = (int*)alloc(65 * 4);

  hipMemsetAsync(cnt, 0, (size_t)NN * 4, stream);
  hipMemsetAsync(fill, 0, (size_t)NN * 4, stream);
  hipMemsetAsync(out, 0, (size_t)NG * HD * 4, stream);

  hist_kernel<<<(NE + 255) / 256, 256, 0, stream>>>(ecol, cnt, NE);
  dinv_kernel<<<(NN + 255) / 256, 256, 0, stream>>>(cnt, dinv, NN);
  int nb = (NN + 255) / 256;  // 196
  scan_partial_kernel<<<nb, 256, 0, stream>>>(cnt, partial, NN);
  scan_scan_kernel<<<1, 256, 0, stream>>>(partial, nb);
  scan_final_kernel<<<nb, 256, 0, stream>>>(cnt, partial, row_ptr, NN, NE);
  scatter_kernel<<<(NE + 255) / 256, 256, 0, stream>>>(erow, ecol, row_ptr, fill, dinv,
                                                       csr_src, csr_w, NE);
  starts_kernel<<<1, 128, 0, stream>>>(batch, gstart, NN, NG);

  cvt_kernel<<<(NN * FIN / 4 + 255) / 256, 256, 0, stream>>>(x, hbuf, NN * FIN / 4);

  for (int L = 0; L < 4; L++) {
    int K = (L == 0) ? FIN : HD;
    const float* W    = (L == 0) ? W0 : Ws + (size_t)(L - 1) * HD * HD;
    const float* bias = (L == 0) ? b0 : bs + (size_t)(L - 1) * HD;
    transpose_w_kernel<<<dim3(HD / 32, K / 32), dim3(32, 8), 0, stream>>>(W, Wt, K, HD);
    gemm_bt_kernel<<<dim3(HD / 128, (NN + 127) / 128), 256, 0, stream>>>(hbuf, Wt, htbuf, NN, K);
    agg_ln_kernel<<<NN / 2, 256, 0, stream>>>(htbuf, row_ptr, csr_src, csr_w, dinv, bias,
                                              gammas + (size_t)L * HD, betas + (size_t)L * HD, hbuf);
  }

  pool_partial_kernel<<<dim3(POOL_CHUNKS, NG), 256, 0, stream>>>(hbuf, gstart, out);
  pool_div_kernel<<<(NG * HD + 255) / 256, 256, 0, stream>>>(out, gstart);
}